// Round 7
// baseline (135.291 us; speedup 1.0000x reference)
//
#include <hip/hip_runtime.h>
#include <hip/hip_bf16.h>
#include <stdint.h>

#define LL 2048
#define SS 2048
#define HH 8
#define EE 64
#define RSG 512   // global row stride in elements (H*E)

typedef float v4f  __attribute__((ext_vector_type(4)));
typedef float v16f __attribute__((ext_vector_type(16)));
typedef short s4v  __attribute__((ext_vector_type(4)));
typedef short s8v  __attribute__((ext_vector_type(8)));

// fp32 -> bf16 bits, round-to-nearest-even
__device__ __forceinline__ short f2bf(float f) {
    unsigned u = __float_as_uint(f);
    u = (u + 0x7fffu + ((u >> 16) & 1u)) >> 16;
    return (short)u;
}

__device__ __forceinline__ s4v pack4bf(float a, float b, float c, float d) {
    float2 ab = make_float2(a, b), cd = make_float2(c, d);
    __hip_bfloat162 r0 = __float22bfloat162_rn(ab);
    __hip_bfloat162 r1 = __float22bfloat162_rn(cd);
    s4v r;
    __builtin_memcpy(&r, &r0, 4);
    __builtin_memcpy(((char*)&r) + 4, &r1, 4);
    return r;
}

// ---------------- prepass ----------------
// Both K and V become per-(b,h,64-row-tile) IMAGES in k-chunk-major order so
// that every main-loop ds_read_b128 and every global_load_lds is fully linear
// (zero bank conflicts, zero XOR address math).
//
// K image: chunk u = echunk*64 + srow  holds K[srow][8*echunk .. +8) as bf16.
// V image: chunk u = c*64 + e          holds V[perm(c,j)][e], j=0..7, with
//   perm(c,j) = 16*(c>>1) + 4*(c&1) + 8*(j>>2) + (j&3)   (the PV k-permutation)
__global__ __launch_bounds__(256)
void dsattn_prep(const float* __restrict__ kk, const float* __restrict__ vv,
                 short* __restrict__ kimg, short* __restrict__ vimg)
{
    __shared__ float T[64][68];
    const int t = threadIdx.x;
    const int blk = blockIdx.x;
    if (blk < 1024) {
        const int vb = blk;                  // (b*8 + h)*32 + ts
        const int b = vb >> 8, h = (vb >> 5) & 7, ts = vb & 31;
        const float* kp = kk + ((size_t)b * SS + ts * 64) * RSG + h * EE;
        #pragma unroll
        for (int c = 0; c < 4; ++c) {
            int idx = c * 256 + t, s = idx >> 4, e0 = (idx & 15) << 2;
            *(v4f*)&T[s][e0] = *(const v4f*)(kp + (size_t)s * RSG + e0);
        }
        __syncthreads();
        short* dst = kimg + (size_t)vb * 4096;
        #pragma unroll
        for (int half = 0; half < 2; ++half) {
            int ci = half * 256 + t;         // chunk u = echunk*64 + srow
            int echunk = ci >> 6, srow = ci & 63;
            s8v ov;
            #pragma unroll
            for (int j = 0; j < 8; ++j) ov[j] = f2bf(T[srow][echunk * 8 + j]);
            *(s8v*)(dst + ci * 8) = ov;
        }
    } else {
        const int vb = blk - 1024;           // (b*8 + h)*32 + ts
        const int b = vb >> 8, h = (vb >> 5) & 7, ts = vb & 31;
        const float* vp = vv + ((size_t)b * SS + ts * 64) * RSG + h * EE;
        #pragma unroll
        for (int c = 0; c < 4; ++c) {
            int idx = c * 256 + t, s = idx >> 4, e0 = (idx & 15) << 2;
            *(v4f*)&T[s][e0] = *(const v4f*)(vp + (size_t)s * RSG + e0);
        }
        __syncthreads();
        short* dst = vimg + (size_t)vb * 4096;
        #pragma unroll
        for (int half = 0; half < 2; ++half) {
            int ci = half * 256 + t;         // chunk u = c*64 + e
            int c = ci >> 6, e = ci & 63;
            int sbase = 16 * (c >> 1) + 4 * (c & 1);
            s8v ov;
            #pragma unroll
            for (int j = 0; j < 8; ++j) {
                int s = sbase + 8 * (j >> 2) + (j & 3);
                ov[j] = f2bf(T[s][e]);
            }
            *(s8v*)(dst + ci * 8) = ov;
        }
    }
}

// ---------------- main: 128 Q rows/block, 8 waves = 2 S-split wave-groups ----
// OCCUPANCY lever: 512-thread blocks.  Wave-group A (waves 0-3) handles
// S-tiles 0..15, group B (waves 4-7) handles 16..31 — same 128 Q rows.
// Each group runs the verified pipeline (2-slot LDS ring, counted vmcnt(4),
// stage-after-compute barrier) on its own 32KB ring: 64KB total -> still
// 2 blocks/CU, but 16 waves/CU (50% occupancy) instead of 8.
// Exact partial combine (no max-tracking -> partial exp sums add exactly)
// through LDS at the end: B publishes oacc+rsum, A adds, normalizes, stores.
// XCD-bijective 1-D grid: each XCD owns 4 contiguous (b,h) panels.
__global__ __launch_bounds__(512, 4)
void dsattn_main(const float* __restrict__ q, const short* __restrict__ kimg,
                 const short* __restrict__ vimg, const float* __restrict__ tau,
                 float* __restrict__ out)
{
    // [grp][slot]: per slot [0..4095] K image, [4096..8191] V image (16KB)
    __shared__ short KV[2][2][8192];        // 64KB

    const int t    = threadIdx.x;
    const int lane = t & 63;
    const int w    = t >> 6;                // 0..7
    const int w4   = w & 3;                 // wave within group
    const int grp  = w >> 2;                // S-split group: 0 -> tiles 0..15, 1 -> 16..31
    const int l31  = lane & 31;
    const int hi   = lane >> 5;

    // XCD-aware decode: 512 blocks, 8 XCDs, 64 consecutive work-units per XCD.
    const int hw = blockIdx.x;
    const int wu = (hw & 7) * 64 + (hw >> 3);
    const int mt = wu & 15;
    const int h  = (wu >> 4) & 7;
    const int b  = wu >> 7;

    const float scf = 0.125f * 1.44269504088896f * tau[b];  // tau*scale*log2e folded into Q

    // ---- Q B-frags: lane holds Q[w4*32+l31][e = 16ks + 8hi + j], pre-scaled ----
    s8v qf[4];
    {
        const float* qb = q + ((size_t)b * LL + (size_t)mt * 128 + w4 * 32 + l31) * RSG
                            + h * EE + 8 * hi;
        #pragma unroll
        for (int ks = 0; ks < 4; ++ks) {
            v4f a0 = *(const v4f*)(qb + 16 * ks);
            v4f a1 = *(const v4f*)(qb + 16 * ks + 4);
            s4v p0 = pack4bf(a0[0] * scf, a0[1] * scf, a0[2] * scf, a0[3] * scf);
            s4v p1 = pack4bf(a1[0] * scf, a1[1] * scf, a1[2] * scf, a1[3] * scf);
            s8v f;
            #pragma unroll
            for (int j = 0; j < 4; ++j) { f[j] = p0[j]; f[4 + j] = p1[j]; }
            qf[ks] = f;
        }
    }

    // ---- staging source: fully linear; group offset = 16 tiles x 8KB ----
    const char* gsrc;
    {
        const size_t pan  = (size_t)((b * 8 + h) * 32) * 8192;  // panel base (bytes)
        const size_t soff = (size_t)grp * 16 * 8192;            // S-split offset
        if (w4 < 2) gsrc = (const char*)kimg + pan + soff + w4 * 4096 + lane * 16;
        else        gsrc = (const char*)vimg + pan + soff + (w4 - 2) * 4096 + lane * 16;
    }

    // one STAGE = 4 loads/wave; group's 4 waves fill one 16KB tile slot
    #define STAGE(slot)                                                                   \
        {                                                                                 \
            _Pragma("unroll")                                                             \
            for (int j = 0; j < 4; ++j) {                                                 \
                __builtin_amdgcn_global_load_lds(                                         \
                    (const __attribute__((address_space(1))) unsigned*)(gsrc + j * 1024), \
                    (__attribute__((address_space(3))) unsigned*)&KV[grp][slot][w4 * 2048 + j * 512], \
                    16, 0, 0);                                                            \
            }                                                                             \
            gsrc += 8192;                                                                 \
        }

    v16f oacc[2];
    #pragma unroll
    for (int mb = 0; mb < 2; ++mb)
        #pragma unroll
        for (int r = 0; r < 16; ++r) oacc[mb][r] = 0.0f;
    float rsum = 0.0f;

    // per-lane fragment offset (shorts): chunk u = (2ks+hi)*64 + mb*32 + l31
    //   -> offset = ks*1024 + mb*256 + rb,  rb = hi*512 + l31*8
    const int rb = hi * 512 + l31 * 8;

    // Drain Q loads so loop vmcnt counts see ONLY staging loads; fill both slots.
    asm volatile("s_waitcnt vmcnt(0)" ::: "memory");
    __builtin_amdgcn_sched_barrier(0);
    STAGE(0);
    STAGE(1);

    #pragma unroll 1
    for (int sw = 0; sw < 16; ++sw) {
        const int p = sw & 1;

        // Outstanding/wave: tiles sw, sw+1 = 8 loads -> vmcnt(4) retires tile sw.
        // Tail sw=15: only 4 outstanding -> vmcnt(0).
        __builtin_amdgcn_sched_barrier(0);
        if (sw <= 14) asm volatile("s_waitcnt vmcnt(4)" ::: "memory");
        else          asm volatile("s_waitcnt vmcnt(0)" ::: "memory");
        __builtin_amdgcn_s_barrier();
        __builtin_amdgcn_sched_barrier(0);

        const short* Kp = &KV[grp][p][0];
        const short* Vp = &KV[grp][p][4096];

        // ---- S^T = K Q^T : 2 s-row-blocks x 4 k-steps ----
        v16f st[2];
        #pragma unroll
        for (int mb = 0; mb < 2; ++mb) {
            v16f z;
            #pragma unroll
            for (int r = 0; r < 16; ++r) z[r] = 0.0f;
            #pragma unroll
            for (int ks = 0; ks < 4; ++ks) {
                s8v kf = *(const s8v*)&Kp[ks * 1024 + mb * 256 + rb];
                z = __builtin_amdgcn_mfma_f32_32x32x16_bf16(kf, qf[ks], z, 0, 0, 0);
            }
            st[mb] = z;
        }

        // ---- exp2 numerator (tau pre-folded, no max-tracking), row sum, pack ----
        #pragma unroll
        for (int mb = 0; mb < 2; ++mb)
            #pragma unroll
            for (int r = 0; r < 16; ++r)
                st[mb][r] = __builtin_amdgcn_exp2f(st[mb][r]);
        float s0 = 0.f, s1 = 0.f;
        #pragma unroll
        for (int r = 0; r < 16; ++r) { s0 += st[0][r]; s1 += st[1][r]; }
        rsum += s0 + s1;

        s8v pf[4];    // B-operand for PV, straight from C-layout registers
        #pragma unroll
        for (int tt = 0; tt < 4; ++tt) {
            int o = 8 * (tt & 1);
            const v16f& sv = st[tt >> 1];
            s4v lo = pack4bf(sv[o + 0], sv[o + 1], sv[o + 2], sv[o + 3]);
            s4v hs = pack4bf(sv[o + 4], sv[o + 5], sv[o + 6], sv[o + 7]);
            s8v f;
            #pragma unroll
            for (int j = 0; j < 4; ++j) { f[j] = lo[j]; f[4 + j] = hs[j]; }
            pf[tt] = f;
        }

        // ---- O^T += V^T P^T : 2 e-row-blocks x 4 k-steps ----
        #pragma unroll
        for (int mb = 0; mb < 2; ++mb) {
            v16f acc = oacc[mb];
            #pragma unroll
            for (int ks = 0; ks < 4; ++ks) {
                s8v vf = *(const s8v*)&Vp[ks * 1024 + mb * 256 + rb];
                acc = __builtin_amdgcn_mfma_f32_32x32x16_bf16(vf, pf[ks], acc, 0, 0, 0);
            }
            oacc[mb] = acc;
        }

        // re-stage the just-computed slot with tile sw+2 (all waves done reading
        // slot p -> barrier); loads fly under the next window's compute
        if (sw <= 13) {
            __builtin_amdgcn_sched_barrier(0);
            __builtin_amdgcn_s_barrier();
            __builtin_amdgcn_sched_barrier(0);
            STAGE(p);
        }
    }

    // ---- exact cross-group combine through LDS, then normalize and store ----
    __syncthreads();                         // all compute + staging complete
    float* sh = (float*)&KV[0][0][0];        // reuse ring storage (33.9KB used)
    const int slot = (t & 255) * 33;         // stride 33 floats: conflict-free
    if (grp == 1) {
        #pragma unroll
        for (int mb = 0; mb < 2; ++mb)
            #pragma unroll
            for (int r = 0; r < 16; ++r) sh[slot + mb * 16 + r] = oacc[mb][r];
        sh[slot + 32] = rsum;
    }
    __syncthreads();
    if (grp == 0) {
        #pragma unroll
        for (int mb = 0; mb < 2; ++mb)
            #pragma unroll
            for (int r = 0; r < 16; ++r) oacc[mb][r] += sh[slot + mb * 16 + r];
        rsum += sh[slot + 32];
        rsum += __shfl_xor(rsum, 32);        // cross-half: other 32 s-rows per tile
        const float inv = 1.0f / rsum;
        float* ob = out + ((size_t)b * LL + (size_t)mt * 128 + w4 * 32 + l31) * RSG + h * EE;
        #pragma unroll
        for (int mb = 0; mb < 2; ++mb)
            #pragma unroll
            for (int rq = 0; rq < 4; ++rq) {
                int e0 = 32 * mb + 8 * rq + 4 * hi;   // C row = (reg&3)+8*(reg>>2)+4*hi
                v4f o4 = { oacc[mb][4 * rq + 0] * inv, oacc[mb][4 * rq + 1] * inv,
                           oacc[mb][4 * rq + 2] * inv, oacc[mb][4 * rq + 3] * inv };
                *(v4f*)(ob + e0) = o4;
            }
    }
}

extern "C" void kernel_launch(void* const* d_in, const int* in_sizes, int n_in,
                              void* d_out, int out_size, void* d_ws, size_t ws_size,
                              hipStream_t stream) {
    const float* q     = (const float*)d_in[0];
    const float* k     = (const float*)d_in[1];
    const float* v     = (const float*)d_in[2];
    // d_in[3] = attn_mask (unused); d_in[5] = delta (drops out of softmax exactly)
    const float* tau   = (const float*)d_in[4];
    float* out = (float*)d_out;

    short* kimg = (short*)d_ws;                   // 4*2048*512 bf16 = 8.39 MB
    short* vimg = kimg + (size_t)4 * SS * RSG;    // 8.39 MB

    dsattn_prep<<<dim3(2048), dim3(256), 0, stream>>>(k, v, kimg, vimg);
    dsattn_main<<<dim3(512), dim3(512), 0, stream>>>(q, kimg, vimg, tau, out);
}